// Round 1
// baseline (94.167 us; speedup 1.0000x reference)
//
#include <hip/hip_runtime.h>
#include <hip/hip_bf16.h>

// ContrastiveLoss: ys [4096,2048] f32, labels [4096] i32 -> scalar f32
// loss = mean over strict lower triangle of: same ? relu(2-cos)^2 : cos^2
// cos = pairwise cosine similarity of rows of ys (norm clamped at 1e-6).

#define ROWS 4096
#define KDIM 2048
#define NTILE 32              // 4096/128
#define NBLK (NTILE * NTILE)  // 1024 (only lower-tri 528 do work)

typedef __bf16 bf16x8 __attribute__((ext_vector_type(8)));
typedef float f32x4 __attribute__((ext_vector_type(4)));

__device__ __forceinline__ unsigned short f2bf(float f) {
    unsigned u = __float_as_uint(f);
    unsigned r = (u + 0x7FFFu + ((u >> 16) & 1u)) >> 16;  // RNE
    return (unsigned short)r;
}

__device__ __forceinline__ void async_copy16(const unsigned short* g, unsigned short* l) {
    __builtin_amdgcn_global_load_lds(
        (const __attribute__((address_space(1))) void*)g,
        (__attribute__((address_space(3))) void*)l,
        16, 0, 0);
}

// ---------------- Kernel 1: row normalize, f32 -> bf16 --------------------
__global__ __launch_bounds__(256) void normalize_rows(
    const float* __restrict__ ys, unsigned short* __restrict__ yn) {
    int row = blockIdx.x;
    const float4* src = (const float4*)(ys + (size_t)row * KDIM);
    float4 vals[2];
    float ss = 0.f;
#pragma unroll
    for (int i = 0; i < 2; ++i) {
        float4 v = src[threadIdx.x + i * 256];
        vals[i] = v;
        ss += v.x * v.x + v.y * v.y + v.z * v.z + v.w * v.w;
    }
#pragma unroll
    for (int off = 32; off > 0; off >>= 1) ss += __shfl_down(ss, off);
    __shared__ float red[4];
    int lane = threadIdx.x & 63, wv = threadIdx.x >> 6;
    if (lane == 0) red[wv] = ss;
    __syncthreads();
    float tot = red[0] + red[1] + red[2] + red[3];
    float inv = 1.0f / fmaxf(sqrtf(tot), 1e-6f);
    ushort4* dst = (ushort4*)(yn + (size_t)row * KDIM);
#pragma unroll
    for (int i = 0; i < 2; ++i) {
        float4 v = vals[i];
        ushort4 o;
        o.x = f2bf(v.x * inv);
        o.y = f2bf(v.y * inv);
        o.z = f2bf(v.z * inv);
        o.w = f2bf(v.w * inv);
        dst[threadIdx.x + i * 256] = o;
    }
}

// ---------------- Kernel 2: 128x128 Gram tile + fused loss ----------------
// Grid (32,32); block 256 = 4 waves in 2x2, each wave owns a 64x64 subtile.
// Only bi >= bj blocks compute (lower triangle incl. diagonal tiles).
__global__ __launch_bounds__(256) void gram_loss(
    const unsigned short* __restrict__ yn, const int* __restrict__ labels,
    float* __restrict__ partials) {
    int bj = blockIdx.x, bi = blockIdx.y;
    int bid = bi * NTILE + bj;
    if (bi < bj) {
        if (threadIdx.x == 0) partials[bid] = 0.f;
        return;
    }

    __shared__ unsigned short As[128 * 64];  // [row][k] 16KB, XOR-swizzled
    __shared__ unsigned short Bs[128 * 64];
    __shared__ int labI[128];
    __shared__ int labJ[128];
    __shared__ float red[4];

    int tid = threadIdx.x, lane = tid & 63, wv = tid >> 6;
    int wr = wv >> 1, wc = wv & 1;
    int rowA = bi * 128, rowB = bj * 128;

    if (tid < 128) labI[tid] = labels[rowA + tid];
    else labJ[tid - 128] = labels[rowB + tid - 128];

    // staging: chunk = 8 rows x 64 cols (1KB). lane covers row lane>>3,
    // granule (lane&7) pre-XORed with row so linear LDS writes land swizzled.
    int srow = lane >> 3;
    int scol = ((lane & 7) ^ srow) * 8;

    f32x4 zero = {0.f, 0.f, 0.f, 0.f};
    f32x4 acc[4][4];
#pragma unroll
    for (int m = 0; m < 4; ++m)
#pragma unroll
        for (int n = 0; n < 4; ++n) acc[m][n] = zero;

    int colB = lane & 15;  // spatial index within 16x16 fragment
    int kq = lane >> 4;    // k-quarter

    for (int k0 = 0; k0 < KDIM; k0 += 64) {
        __syncthreads();  // previous tile fully consumed (and labels visible)
#pragma unroll
        for (int it = 0; it < 4; ++it) {
            int chunk = it * 4 + wv;
            int r = chunk * 8 + srow;
            const unsigned short* ga = yn + (size_t)(rowA + r) * KDIM + k0 + scol;
            async_copy16(ga, As + chunk * 512);
            const unsigned short* gb = yn + (size_t)(rowB + r) * KDIM + k0 + scol;
            async_copy16(gb, Bs + chunk * 512);
        }
        __syncthreads();  // vmcnt(0) drained by syncthreads semantics

#pragma unroll
        for (int kk = 0; kk < 64; kk += 32) {
            int kidx = kk + 8 * kq;
            bf16x8 af[4], bfr[4];
#pragma unroll
            for (int m = 0; m < 4; ++m) {
                int row = wr * 64 + m * 16 + colB;
                int byte = (row * 128 + kidx * 2) ^ ((row & 7) << 4);
                af[m] = *(const bf16x8*)((const char*)As + byte);
            }
#pragma unroll
            for (int n = 0; n < 4; ++n) {
                int row = wc * 64 + n * 16 + colB;
                int byte = (row * 128 + kidx * 2) ^ ((row & 7) << 4);
                bfr[n] = *(const bf16x8*)((const char*)Bs + byte);
            }
#pragma unroll
            for (int m = 0; m < 4; ++m)
#pragma unroll
                for (int n = 0; n < 4; ++n)
                    acc[m][n] = __builtin_amdgcn_mfma_f32_16x16x32_bf16(
                        af[m], bfr[n], acc[m][n], 0, 0, 0);
        }
    }

    // fused loss epilogue: C[ti][tj], ti = wr*64+m*16+kq*4+j, tj = wc*64+n*16+colB
    float lsum = 0.f;
#pragma unroll
    for (int m = 0; m < 4; ++m) {
#pragma unroll
        for (int n = 0; n < 4; ++n) {
#pragma unroll
            for (int j = 0; j < 4; ++j) {
                int ti = wr * 64 + m * 16 + kq * 4 + j;
                int tj = wc * 64 + n * 16 + colB;
                int gi = rowA + ti, gj = rowB + tj;
                if (gi > gj) {
                    float c = acc[m][n][j];
                    float v = (labI[ti] == labJ[tj]) ? fmaxf(2.0f - c, 0.0f) : c;
                    lsum += v * v;
                }
            }
        }
    }
#pragma unroll
    for (int off = 32; off > 0; off >>= 1) lsum += __shfl_down(lsum, off);
    if (lane == 0) red[wv] = lsum;
    __syncthreads();
    if (tid == 0) partials[bid] = red[0] + red[1] + red[2] + red[3];
}

// ---------------- Kernel 3: deterministic final reduction -----------------
__global__ __launch_bounds__(256) void finalize(
    const float* __restrict__ partials, float* __restrict__ out) {
    float s = 0.f;
    for (int i = threadIdx.x; i < NBLK; i += 256) s += partials[i];
#pragma unroll
    for (int off = 32; off > 0; off >>= 1) s += __shfl_down(s, off);
    __shared__ float red[4];
    int lane = threadIdx.x & 63, wv = threadIdx.x >> 6;
    if (lane == 0) red[wv] = s;
    __syncthreads();
    if (threadIdx.x == 0) {
        const double npair = (double)ROWS * (ROWS - 1) / 2.0;
        out[0] = (float)((double)(red[0] + red[1] + red[2] + red[3]) / npair);
    }
}

extern "C" void kernel_launch(void* const* d_in, const int* in_sizes, int n_in,
                              void* d_out, int out_size, void* d_ws, size_t ws_size,
                              hipStream_t stream) {
    const float* ys = (const float*)d_in[0];
    const int* labels = (const int*)d_in[1];
    float* out = (float*)d_out;

    unsigned short* yn = (unsigned short*)d_ws;                       // 16 MB bf16
    float* partials = (float*)((char*)d_ws + (size_t)ROWS * KDIM * 2);  // 4 KB

    normalize_rows<<<ROWS, 256, 0, stream>>>(ys, yn);
    dim3 grid(NTILE, NTILE);
    gram_loss<<<grid, 256, 0, stream>>>(yn, labels, partials);
    finalize<<<1, 256, 0, stream>>>(partials, out);
}

// Round 2
// 75.783 us; speedup vs baseline: 1.2426x; 1.2426x over previous
//
#include <hip/hip_runtime.h>
#include <hip/hip_bf16.h>

// ContrastiveLoss: ys [4096,2048] f32, labels [4096] i32 -> scalar f32
// loss = mean over strict lower triangle of: same ? relu(2-cos)^2 : cos^2
// cos = pairwise cosine similarity of rows of ys (norm clamped at 1e-6).

#define ROWS 4096
#define KDIM 2048
// Tile decomposition: 128-row x 64-col tiles over the lower triangle.
// bi in [0,32), bj in [0,64); keep bj <= 2*bi+1  -> sum(2bi+2) = 1056 jobs.
#define NJOBS 1056

typedef __bf16 bf16x8 __attribute__((ext_vector_type(8)));
typedef float f32x4 __attribute__((ext_vector_type(4)));

__device__ __forceinline__ unsigned short f2bf(float f) {
    unsigned u = __float_as_uint(f);
    unsigned r = (u + 0x7FFFu + ((u >> 16) & 1u)) >> 16;  // RNE
    return (unsigned short)r;
}

__device__ __forceinline__ void async_copy16(const unsigned short* g, unsigned short* l) {
    __builtin_amdgcn_global_load_lds(
        (const __attribute__((address_space(1))) void*)g,
        (__attribute__((address_space(3))) void*)l,
        16, 0, 0);
}

// ---------------- Kernel 1: row normalize, f32 -> bf16 --------------------
__global__ __launch_bounds__(256) void normalize_rows(
    const float* __restrict__ ys, unsigned short* __restrict__ yn) {
    int row = blockIdx.x;
    const float4* src = (const float4*)(ys + (size_t)row * KDIM);
    float4 vals[2];
    float ss = 0.f;
#pragma unroll
    for (int i = 0; i < 2; ++i) {
        float4 v = src[threadIdx.x + i * 256];
        vals[i] = v;
        ss += v.x * v.x + v.y * v.y + v.z * v.z + v.w * v.w;
    }
#pragma unroll
    for (int off = 32; off > 0; off >>= 1) ss += __shfl_down(ss, off);
    __shared__ float red[4];
    int lane = threadIdx.x & 63, wv = threadIdx.x >> 6;
    if (lane == 0) red[wv] = ss;
    __syncthreads();
    float tot = red[0] + red[1] + red[2] + red[3];
    float inv = 1.0f / fmaxf(sqrtf(tot), 1e-6f);
    ushort4* dst = (ushort4*)(yn + (size_t)row * KDIM);
#pragma unroll
    for (int i = 0; i < 2; ++i) {
        float4 v = vals[i];
        ushort4 o;
        o.x = f2bf(v.x * inv);
        o.y = f2bf(v.y * inv);
        o.z = f2bf(v.z * inv);
        o.w = f2bf(v.w * inv);
        dst[threadIdx.x + i * 256] = o;
    }
}

// ---------------- Kernel 2: 128x64 Gram tile + fused loss -----------------
// 1056 linear blocks -> (bi,bj) lower-triangle jobs. 4 waves in 2x2; each
// wave owns a 64x32 subtile (4x2 frags of 16x16, acc = 8 f32x4).
__global__ __launch_bounds__(256) void gram_loss(
    const unsigned short* __restrict__ yn, const int* __restrict__ labels,
    float* __restrict__ partials) {
    // XCD-chunk swizzle (bijective: 1056 % 8 == 0, 132 jobs per XCD):
    int t = (blockIdx.x & 7) * (NJOBS / 8) + (blockIdx.x >> 3);
    // job t -> (bi, bj): jobs for bi occupy [bi*(bi+1), bi*(bi+1)+2bi+2)
    int bi = (int)((sqrtf((float)(4 * t + 1)) - 1.0f) * 0.5f);
    while (bi * (bi + 1) > t) --bi;
    while ((bi + 1) * (bi + 2) <= t) ++bi;
    int bj = t - bi * (bi + 1);

    __shared__ unsigned short As[128 * 64];  // [row][k] 16KB, XOR-swizzled
    __shared__ unsigned short Bs[64 * 64];   // 8KB
    __shared__ int labI[128];
    __shared__ int labJ[64];
    __shared__ float red[4];

    int tid = threadIdx.x, lane = tid & 63, wv = tid >> 6;
    int wr = wv >> 1, wc = wv & 1;
    int rowA = bi * 128, rowB = bj * 64;

    if (tid < 128) labI[tid] = labels[rowA + tid];
    else if (tid < 192) labJ[tid - 128] = labels[rowB + tid - 128];

    // staging: chunk = 8 rows x 64 cols (1KB). lane covers row lane>>3,
    // granule (lane&7) pre-XORed with row so linear LDS writes land swizzled.
    int srow = lane >> 3;
    int scol = ((lane & 7) ^ srow) * 8;

    f32x4 zero = {0.f, 0.f, 0.f, 0.f};
    f32x4 acc[4][2];
#pragma unroll
    for (int m = 0; m < 4; ++m)
#pragma unroll
        for (int n = 0; n < 2; ++n) acc[m][n] = zero;

    int colB = lane & 15;  // spatial index within 16x16 fragment
    int kq = lane >> 4;    // k-quarter

    for (int k0 = 0; k0 < KDIM; k0 += 64) {
        __syncthreads();  // previous tile fully consumed
        // 24 chunks: 0..15 -> A (16KB), 16..23 -> B (8KB); 6 iters x 4 waves
#pragma unroll
        for (int it = 0; it < 6; ++it) {
            int chunk = it * 4 + wv;
            int r = (chunk & 15) * 8 + srow;  // (chunk-16)*8 for B == (chunk&15)*8? no:
            if (chunk < 16) {
                int rr = chunk * 8 + srow;
                const unsigned short* ga = yn + (size_t)(rowA + rr) * KDIM + k0 + scol;
                async_copy16(ga, As + chunk * 512);
            } else {
                int c2 = chunk - 16;
                int rr = c2 * 8 + srow;
                const unsigned short* gb = yn + (size_t)(rowB + rr) * KDIM + k0 + scol;
                async_copy16(gb, Bs + c2 * 512);
            }
            (void)r;
        }
        __syncthreads();  // vmcnt(0) drained by syncthreads semantics

#pragma unroll
        for (int kk = 0; kk < 64; kk += 32) {
            int kidx = kk + 8 * kq;
            bf16x8 af[4], bfr[2];
#pragma unroll
            for (int m = 0; m < 4; ++m) {
                int row = wr * 64 + m * 16 + colB;
                int byte = (row * 128 + kidx * 2) ^ ((row & 7) << 4);
                af[m] = *(const bf16x8*)((const char*)As + byte);
            }
#pragma unroll
            for (int n = 0; n < 2; ++n) {
                int row = wc * 32 + n * 16 + colB;
                int byte = (row * 128 + kidx * 2) ^ ((row & 7) << 4);
                bfr[n] = *(const bf16x8*)((const char*)Bs + byte);
            }
#pragma unroll
            for (int m = 0; m < 4; ++m)
#pragma unroll
                for (int n = 0; n < 2; ++n)
                    acc[m][n] = __builtin_amdgcn_mfma_f32_16x16x32_bf16(
                        af[m], bfr[n], acc[m][n], 0, 0, 0);
        }
    }

    // fused loss epilogue: ti = wr*64+m*16+kq*4+j, tj = wc*32+n*16+colB
    float lsum = 0.f;
#pragma unroll
    for (int m = 0; m < 4; ++m) {
#pragma unroll
        for (int n = 0; n < 2; ++n) {
#pragma unroll
            for (int j = 0; j < 4; ++j) {
                int ti = wr * 64 + m * 16 + kq * 4 + j;
                int tj = wc * 32 + n * 16 + colB;
                int gi = rowA + ti, gj = rowB + tj;
                if (gi > gj) {
                    float c = acc[m][n][j];
                    float v = (labI[ti] == labJ[tj]) ? fmaxf(2.0f - c, 0.0f) : c;
                    lsum += v * v;
                }
            }
        }
    }
#pragma unroll
    for (int off = 32; off > 0; off >>= 1) lsum += __shfl_down(lsum, off);
    if (lane == 0) red[wv] = lsum;
    __syncthreads();
    if (tid == 0) partials[blockIdx.x] = red[0] + red[1] + red[2] + red[3];
}

// ---------------- Kernel 3: deterministic final reduction -----------------
__global__ __launch_bounds__(256) void finalize(
    const float* __restrict__ partials, float* __restrict__ out) {
    float s = 0.f;
    for (int i = threadIdx.x; i < NJOBS; i += 256) s += partials[i];
#pragma unroll
    for (int off = 32; off > 0; off >>= 1) s += __shfl_down(s, off);
    __shared__ float red[4];
    int lane = threadIdx.x & 63, wv = threadIdx.x >> 6;
    if (lane == 0) red[wv] = s;
    __syncthreads();
    if (threadIdx.x == 0) {
        const double npair = (double)ROWS * (ROWS - 1) / 2.0;
        out[0] = (float)((double)(red[0] + red[1] + red[2] + red[3]) / npair);
    }
}

extern "C" void kernel_launch(void* const* d_in, const int* in_sizes, int n_in,
                              void* d_out, int out_size, void* d_ws, size_t ws_size,
                              hipStream_t stream) {
    const float* ys = (const float*)d_in[0];
    const int* labels = (const int*)d_in[1];
    float* out = (float*)d_out;

    unsigned short* yn = (unsigned short*)d_ws;                         // 16 MB bf16
    float* partials = (float*)((char*)d_ws + (size_t)ROWS * KDIM * 2);  // 4.2 KB

    normalize_rows<<<ROWS, 256, 0, stream>>>(ys, yn);
    gram_loss<<<NJOBS, 256, 0, stream>>>(yn, labels, partials);
    finalize<<<1, 256, 0, stream>>>(partials, out);
}